// Round 5
// baseline (183.977 us; speedup 1.0000x reference)
//
#include <hip/hip_runtime.h>
#include <cstdint>
#include <cstddef>

#define NTOK 8192
#define DIN  1024
#define DH   128
#define KVB  64

typedef __attribute__((ext_vector_type(4))) float f32x4;
typedef __attribute__((ext_vector_type(16))) float f32x16;
typedef __bf16 bf16x8 __attribute__((ext_vector_type(8)));
typedef unsigned short u16x8 __attribute__((ext_vector_type(8)));
typedef unsigned int u32x4 __attribute__((ext_vector_type(4)));

__device__ __forceinline__ unsigned short f2bf(float f){
  union { float f; unsigned u; } x; x.f = f;
  unsigned r = x.u + 0x7FFFu + ((x.u >> 16) & 1u);
  return (unsigned short)(r >> 16);
}
__device__ __forceinline__ float bf2f(unsigned short b){
  union { unsigned u; float f; } x; x.u = ((unsigned)b) << 16;
  return x.f;
}
__device__ __forceinline__ unsigned cvtpk_bf16(float lo, float hi){
  unsigned r;
  asm volatile("v_cvt_pk_bf16_f32 %0, %1, %2" : "=v"(r) : "v"(lo), "v"(hi));
  return r;
}
// async global->LDS, 16B per lane. LDS dest = wave-uniform base + lane*16 (HW).
__device__ __forceinline__ void gload16(const void* g, void* l){
  using gp_t = const __attribute__((address_space(1))) char*;
  using lp_t = __attribute__((address_space(3))) char*;
  __builtin_amdgcn_global_load_lds((gp_t)(uintptr_t)g, (lp_t)(uint32_t)(uintptr_t)l, 16, 0, 0);
}

// ---------- kernel 1: split W into hi/lo bf16, transposed to [384][1024]
__global__ void k_wsplit(const float* __restrict__ Wq, const float* __restrict__ Wk,
                         const float* __restrict__ Wv,
                         unsigned short* __restrict__ WhT, unsigned short* __restrict__ WlT){
  int e = blockIdx.x * 256 + threadIdx.x;   // 384*1024 threads
  int n = e >> 10, k = e & 1023;
  const float* W = (n < 128) ? Wq : ((n < 256) ? Wk : Wv);
  float v = W[(size_t)k * 128 + (n & 127)];
  unsigned short h = f2bf(v);
  WhT[e] = h;
  WlT[e] = f2bf(v - bf2f(h));
}

// ---------- kernel 1b: split x into hi/lo bf16 (row-major [8192][1024])
__global__ void k_xsplit(const float* __restrict__ x,
                         unsigned short* __restrict__ xh, unsigned short* __restrict__ xl){
  size_t i = ((size_t)blockIdx.x * 256 + threadIdx.x) * 8;
  f32x4 a = *(const f32x4*)(x + i);
  f32x4 b = *(const f32x4*)(x + i + 4);
  u16x8 h, l;
  #pragma unroll
  for (int j = 0; j < 4; ++j){
    unsigned short h0 = f2bf(a[j]); h[j] = h0;   l[j]   = f2bf(a[j] - bf2f(h0));
    unsigned short h1 = f2bf(b[j]); h[4+j] = h1; l[4+j] = f2bf(b[j] - bf2f(h1));
  }
  *(u16x8*)(xh + i) = h;
  *(u16x8*)(xl + i) = l;
}

// ---------- kernel 2: QKV projection, m97-structure LDS-staged GEMM (unchanged).
__global__ __launch_bounds__(256, 3) void k_proj(
    const unsigned short* __restrict__ xh, const unsigned short* __restrict__ xl,
    const unsigned short* __restrict__ WhT, const unsigned short* __restrict__ WlT,
    unsigned short* __restrict__ Qh, unsigned short* __restrict__ Ql,
    unsigned short* __restrict__ Kh, unsigned short* __restrict__ Kl,
    unsigned short* __restrict__ Vt){
  __shared__ __align__(16) char smem[32768];
  const int lane = threadIdx.x & 63, wid = threadIdx.x >> 6;
  const int l15 = lane & 15, lk = lane >> 4;
  const int bm = blockIdx.x;
  const int by = blockIdx.y;
  const int bt = by >> 1, nh = by & 1;
  const int wm = wid >> 1, wn = wid & 1;

  const int srow = lane >> 3;
  const int gc8  = (lane & 7) ^ srow;
  const unsigned short* gsrc;
  char* ldst;
  int grow0;
  if (wid == 0){      gsrc = xh;  grow0 = bm*64;            ldst = smem; }
  else if (wid == 1){ gsrc = xl;  grow0 = bm*64;            ldst = smem + 8192; }
  else if (wid == 2){ gsrc = WhT; grow0 = bt*128 + nh*64;   ldst = smem + 16384; }
  else {              gsrc = WlT; grow0 = bt*128 + nh*64;   ldst = smem + 24576; }
  const unsigned short* gbase = gsrc + (size_t)(grow0 + srow)*DIN + gc8*8;
  const bool stage_on = (bt < 2) || (wid == 0) || (wid == 2);   // V skips lo tiles

  f32x4 acc[2][2] = {};

  for (int t = 0; t < 16; ++t){
    if (stage_on){
      #pragma unroll
      for (int i = 0; i < 8; ++i)
        gload16(gbase + (size_t)i*8*DIN + t*64, ldst + i*1024);
    }
    __syncthreads();

    bf16x8 a_h[2][2], a_l[2][2], b_h[2][2], b_l[2][2];
    const unsigned sw = (unsigned)(l15 & 7);
    #pragma unroll
    for (int mf = 0; mf < 2; ++mf)
      #pragma unroll
      for (int kc = 0; kc < 2; ++kc){
        unsigned rA = (unsigned)(wm*32 + mf*16 + l15);
        unsigned offA = rA*128u + ((((unsigned)(kc*4 + lk)) ^ sw)*16u);
        a_h[mf][kc] = *(const bf16x8*)(const void*)(smem + offA);
        unsigned rB = (unsigned)(wn*32 + mf*16 + l15);
        unsigned offB = rB*128u + ((((unsigned)(kc*4 + lk)) ^ sw)*16u);
        b_h[mf][kc] = *(const bf16x8*)(const void*)(smem + 16384 + offB);
        if (bt < 2){
          a_l[mf][kc] = *(const bf16x8*)(const void*)(smem + 8192 + offA);
          b_l[mf][kc] = *(const bf16x8*)(const void*)(smem + 24576 + offB);
        }
      }
    #pragma unroll
    for (int mf = 0; mf < 2; ++mf)
      #pragma unroll
      for (int nf = 0; nf < 2; ++nf)
        #pragma unroll
        for (int kc = 0; kc < 2; ++kc){
          acc[mf][nf] = __builtin_amdgcn_mfma_f32_16x16x32_bf16(a_h[mf][kc], b_h[nf][kc], acc[mf][nf], 0,0,0);
          if (bt < 2){
            acc[mf][nf] = __builtin_amdgcn_mfma_f32_16x16x32_bf16(a_h[mf][kc], b_l[nf][kc], acc[mf][nf], 0,0,0);
            acc[mf][nf] = __builtin_amdgcn_mfma_f32_16x16x32_bf16(a_l[mf][kc], b_h[nf][kc], acc[mf][nf], 0,0,0);
          }
        }
    __syncthreads();
  }

  const float qscale = 0.08838834764831845f;  // 1/sqrt(128), folded into Q
  #pragma unroll
  for (int mf = 0; mf < 2; ++mf){
    #pragma unroll
    for (int nf = 0; nf < 2; ++nf){
      #pragma unroll
      for (int r = 0; r < 4; ++r){
        int row = bm*64 + wm*32 + mf*16 + lk*4 + r;
        int col = nh*64 + wn*32 + nf*16 + l15;
        float v = acc[mf][nf][r];
        if (bt == 0){
          v *= qscale;
          unsigned short h = f2bf(v);
          Qh[(size_t)row*DH + col] = h;
          Ql[(size_t)row*DH + col] = f2bf(v - bf2f(h));
        } else if (bt == 1){
          unsigned short h = f2bf(v);
          Kh[(size_t)row*DH + col] = h;
          Kl[(size_t)row*DH + col] = f2bf(v - bf2f(h));
        } else {
          Vt[(size_t)col*NTOK + row] = f2bf(v);   // V^T [128][8192]
        }
      }
    }
  }
}

// ---------- kernel 3: flash attention partials, 32x32x16 MFMA, 32 q/wave.
// 256 thr = 4 waves x 32 q (block 128 q). KVB=64. LDS 48KB single buffer:
//   Kh[64][128]swz | Kl[64][128]swz | Vt[128][64]swz.  P stays in registers
//   (cvt_pk_bf16 + shfl_xor(32) half-exchange builds PV B-fragments).
__global__ __launch_bounds__(256, 2) void k_flash(
    const unsigned short* __restrict__ Qh, const unsigned short* __restrict__ Ql,
    const unsigned short* __restrict__ Kh, const unsigned short* __restrict__ Kl,
    const unsigned short* __restrict__ Vt,
    float* __restrict__ Opart, float* __restrict__ mpart, float* __restrict__ lpart,
    int ksplit){
  __shared__ __align__(16) char smem[49152];
  char* smemc = smem;
  const int tid = threadIdx.x;
  const int lane = tid & 63, wid = tid >> 6;
  const int l31 = lane & 31, hi = lane >> 5;
  const int qb = blockIdx.x / ksplit, ks = blockIdx.x - qb*ksplit;
  const int q0w = qb*128 + wid*32;
  const int kvlen = NTOK / ksplit;
  const int kvbase = ks * kvlen;
  const int NT = kvlen / KVB;

  // Q fragments (B-operand, 32x32x16): lane holds Q[q0w+l31][kc*16 + hi*8 ..+7]
  bf16x8 qh[8], ql[8];
  #pragma unroll
  for (int kc = 0; kc < 8; ++kc){
    size_t off = (size_t)(q0w + l31)*DH + kc*16 + hi*8;
    qh[kc] = *(const bf16x8*)(const void*)(Qh + off);
    ql[kc] = *(const bf16x8*)(const void*)(Ql + off);
  }

  // staging: wave w stages 1KB-groups 4w..4w+3 of each of Kh, Kl, Vt.
  // K group g: rows 4g..4g+3 of [64][128]; lane -> row 4g+(lane>>4), slot lane&15,
  //   global granule = slot ^ (row&7). V group g: rows 8g..8g+7 of [128][64];
  //   lane -> row 8g+(lane>>3), slot lane&7, global granule = slot ^ (lane>>3).
  int gK[4], gV[4], ldsO[4];
  #pragma unroll
  for (int i = 0; i < 4; ++i){
    int g = 4*wid + i;
    int rk = 4*g + (lane >> 4);
    gK[i] = rk*DH + (((lane & 15) ^ (rk & 7))*8);
    int rv = 8*g + (lane >> 3);
    gV[i] = rv*NTOK + (((lane & 7) ^ (lane >> 3))*8);
    ldsO[i] = g*1024;
  }

  #define STAGE(kv0_) do { int _o = (kv0_)*DH;                          \
    _Pragma("unroll")                                                   \
    for (int i = 0; i < 4; ++i){                                        \
      gload16(Kh + (size_t)(_o + gK[i]), smemc + ldsO[i]);              \
      gload16(Kl + (size_t)(_o + gK[i]), smemc + 16384 + ldsO[i]);      \
      gload16(Vt + (size_t)(gV[i] + (kv0_)), smemc + 32768 + ldsO[i]);  \
    } } while(0)

  STAGE(kvbase);
  __syncthreads();

  f32x16 o[4] = {};
  float m_run = -3.0e38f, l_run = 0.f;

  for (int t = 0; t < NT; ++t){
    // ---- S^T = K·Q^T (hh + lh + hl), two 32-kv blocks
    f32x16 s0 = {}, s1 = {};
    __builtin_amdgcn_s_setprio(1);
    #pragma unroll
    for (int kc = 0; kc < 8; ++kc){
      int r0 = l31;
      unsigned off0 = (unsigned)r0*256u + ((((unsigned)(kc*2 + hi)) ^ (unsigned)(r0 & 7))*16u);
      bf16x8 kh0 = *(const bf16x8*)(const void*)(smemc + off0);
      bf16x8 kl0 = *(const bf16x8*)(const void*)(smemc + 16384 + off0);
      s0 = __builtin_amdgcn_mfma_f32_32x32x16_bf16(kh0, qh[kc], s0, 0,0,0);
      s0 = __builtin_amdgcn_mfma_f32_32x32x16_bf16(kl0, qh[kc], s0, 0,0,0);
      s0 = __builtin_amdgcn_mfma_f32_32x32x16_bf16(kh0, ql[kc], s0, 0,0,0);
      int r1 = 32 + l31;
      unsigned off1 = (unsigned)r1*256u + ((((unsigned)(kc*2 + hi)) ^ (unsigned)(r1 & 7))*16u);
      bf16x8 kh1 = *(const bf16x8*)(const void*)(smemc + off1);
      bf16x8 kl1 = *(const bf16x8*)(const void*)(smemc + 16384 + off1);
      s1 = __builtin_amdgcn_mfma_f32_32x32x16_bf16(kh1, qh[kc], s1, 0,0,0);
      s1 = __builtin_amdgcn_mfma_f32_32x32x16_bf16(kl1, qh[kc], s1, 0,0,0);
      s1 = __builtin_amdgcn_mfma_f32_32x32x16_bf16(kh1, ql[kc], s1, 0,0,0);
    }
    __builtin_amdgcn_s_setprio(0);

    // ---- online softmax: lane holds 32 logits (kv rows) for q = q0w + l31
    float pmax = s0[0];
    #pragma unroll
    for (int i = 1; i < 16; ++i) pmax = fmaxf(pmax, s0[i]);
    #pragma unroll
    for (int i = 0; i < 16; ++i) pmax = fmaxf(pmax, s1[i]);
    pmax = fmaxf(pmax, __shfl_xor(pmax, 32));
    if (!__all(pmax - m_run <= 8.f)){       // defer-max: rescale only on real growth
      float mnew = fmaxf(m_run, pmax);
      float corr = __expf(m_run - mnew);
      l_run *= corr;
      #pragma unroll
      for (int dblk = 0; dblk < 4; ++dblk)
        #pragma unroll
        for (int i = 0; i < 16; ++i) o[dblk][i] *= corr;
      m_run = mnew;
    }
    float tsum = 0.f;
    #pragma unroll
    for (int i = 0; i < 16; ++i){ s0[i] = __expf(s0[i] - m_run); tsum += s0[i]; }
    #pragma unroll
    for (int i = 0; i < 16; ++i){ s1[i] = __expf(s1[i] - m_run); tsum += s1[i]; }
    tsum += __shfl_xor(tsum, 32);
    l_run += tsum;

    // ---- PV: build P^T B-frags in registers (pack + half-exchange), accumulate O^T
    __builtin_amdgcn_s_setprio(1);
    #pragma unroll
    for (int b = 0; b < 4; ++b){            // kv-16 blocks of the 64-kv tile
      f32x16 sv = (b & 2) ? s1 : s0;
      const int base = 8*(b & 1);
      unsigned w0 = cvtpk_bf16(sv[base+0], sv[base+1]);
      unsigned w1 = cvtpk_bf16(sv[base+2], sv[base+3]);
      unsigned w2 = cvtpk_bf16(sv[base+4], sv[base+5]);
      unsigned w3 = cvtpk_bf16(sv[base+6], sv[base+7]);
      unsigned sx0 = (unsigned)__shfl_xor((int)w0, 32);
      unsigned sx1 = (unsigned)__shfl_xor((int)w1, 32);
      unsigned sx2 = (unsigned)__shfl_xor((int)w2, 32);
      unsigned sx3 = (unsigned)__shfl_xor((int)w3, 32);
      u32x4 pw;
      pw[0] = hi ? sx2 : w0;
      pw[1] = hi ? sx3 : w1;
      pw[2] = hi ? w2 : sx0;
      pw[3] = hi ? w3 : sx1;
      bf16x8 pB = __builtin_bit_cast(bf16x8, pw);
      #pragma unroll
      for (int dblk = 0; dblk < 4; ++dblk){
        int rv = dblk*32 + l31;
        unsigned offv = 32768u + (unsigned)rv*128u +
                        ((((unsigned)(b*2 + hi)) ^ (unsigned)(rv & 7))*16u);
        bf16x8 vf = *(const bf16x8*)(const void*)(smemc + offv);
        o[dblk] = __builtin_amdgcn_mfma_f32_32x32x16_bf16(vf, pB, o[dblk], 0,0,0);
      }
    }
    __builtin_amdgcn_s_setprio(0);

    __syncthreads();                        // all waves done reading this tile
    if (t + 1 < NT) STAGE(kvbase + (t+1)*KVB);
    __syncthreads();                        // vmcnt(0) drain -> next tile visible
  }
  #undef STAGE

  // ---- epilogue: unnormalized O^T fragments -> Opart[q][d]
  float* Op = Opart + ((size_t)ks*NTOK + q0w + l31)*DH;
  #pragma unroll
  for (int dblk = 0; dblk < 4; ++dblk)
    #pragma unroll
    for (int g = 0; g < 4; ++g){
      f32x4 q4 = { o[dblk][4*g+0], o[dblk][4*g+1], o[dblk][4*g+2], o[dblk][4*g+3] };
      *(f32x4*)(Op + dblk*32 + 8*g + 4*hi) = q4;
    }
  if (hi == 0){
    mpart[(size_t)ks*NTOK + q0w + l31] = m_run;
    lpart[(size_t)ks*NTOK + q0w + l31] = l_run;
  }
}

// ---------- kernel 4: merge ksplit partials. grid NTOK*32/256, 256 thr.
__global__ void k_merge(const float* __restrict__ Opart, const float* __restrict__ mpart,
                        const float* __restrict__ lpart, float* __restrict__ out, int ksplit){
  int gid = blockIdx.x*256 + threadIdx.x;   // NTOK*32
  int n = gid >> 5, c4 = (gid & 31) * 4;
  float M = -1e30f;
  for (int ks = 0; ks < ksplit; ++ks) M = fmaxf(M, mpart[(size_t)ks*NTOK + n]);
  float L = 0.f;
  f32x4 acc = {0.f, 0.f, 0.f, 0.f};
  for (int ks = 0; ks < ksplit; ++ks){
    float w = __expf(mpart[(size_t)ks*NTOK + n] - M);
    L += lpart[(size_t)ks*NTOK + n] * w;
    f32x4 op = *(const f32x4*)(Opart + ((size_t)ks*NTOK + n)*DH + c4);
    acc += op * w;
  }
  float inv = 1.f / L;
  *(f32x4*)(out + (size_t)n*DH + c4) = acc * inv;
}

extern "C" void kernel_launch(void* const* d_in, const int* in_sizes, int n_in,
                              void* d_out, int out_size, void* d_ws, size_t ws_size,
                              hipStream_t stream){
  const float* x  = (const float*)d_in[0];
  const float* Wq = (const float*)d_in[1];
  const float* Wk = (const float*)d_in[2];
  const float* Wv = (const float*)d_in[3];
  float* out = (float*)d_out;

  char* ws = (char*)d_ws;
  const size_t SZ_WT = (size_t)384*1024*2;        // 768 KB
  const size_t SZ_X  = (size_t)NTOK*DIN*2;        // 16.78 MB
  const size_t SZ_QK = (size_t)NTOK*DH*2;         // 2 MB
  size_t off = 0;
  unsigned short* WhT = (unsigned short*)(ws + off); off += SZ_WT;
  unsigned short* WlT = (unsigned short*)(ws + off); off += SZ_WT;
  unsigned short* xh  = (unsigned short*)(ws + off); off += SZ_X;
  unsigned short* xl  = (unsigned short*)(ws + off); off += SZ_X;
  unsigned short* Qh  = (unsigned short*)(ws + off); off += SZ_QK;
  unsigned short* Ql  = (unsigned short*)(ws + off); off += SZ_QK;
  unsigned short* Kh  = (unsigned short*)(ws + off); off += SZ_QK;
  unsigned short* Kl  = (unsigned short*)(ws + off); off += SZ_QK;
  unsigned short* Vt  = (unsigned short*)(ws + off); off += SZ_QK;

  int ksplit = 8;
  while (ksplit > 1 &&
         off + (size_t)ksplit*(NTOK*(size_t)DH*4 + 2*NTOK*4) > ws_size)
    ksplit >>= 1;
  float* Opart = (float*)(ws + off); off += (size_t)ksplit*NTOK*DH*4;
  float* mpart = (float*)(ws + off); off += (size_t)ksplit*NTOK*4;
  float* lpart = (float*)(ws + off); off += (size_t)ksplit*NTOK*4;

  k_wsplit<<<dim3((384*1024)/256), dim3(256), 0, stream>>>(Wq, Wk, Wv, WhT, WlT);
  k_xsplit<<<dim3((NTOK*DIN)/(256*8)), dim3(256), 0, stream>>>(x, xh, xl);
  k_proj  <<<dim3(NTOK/64, 6), dim3(256), 0, stream>>>(xh, xl, WhT, WlT, Qh, Ql, Kh, Kl, Vt);
  k_flash <<<dim3((NTOK/128)*ksplit), dim3(256), 0, stream>>>(Qh, Ql, Kh, Kl, Vt,
                                                              Opart, mpart, lpart, ksplit);
  k_merge <<<dim3(NTOK*32/256), dim3(256), 0, stream>>>(Opart, mpart, lpart, out, ksplit);
}